// Round 4
// baseline (202.517 us; speedup 1.0000x reference)
//
#include <hip/hip_runtime.h>
#include <stdint.h>

// Problem constants
#define AA 144          // ATOM*ATOM
#define LAM 0.1f

// ---- workspace layout (float offsets) ----
#define OFS_SC    0            // 64 scalars: [16]=scX*mu, [17]=scA, [18]=-scA*mu
#define OFS_AF1   64           // 128*144 row-normalized zero-mean atoms
#define OFS_G     36928        // 128*128 gram (f32)
#define OFS_S0    53312        // ATB (bf16 -mu*atoms_n, [128][160] u16, natural order)
#define OFS_S1    69696        // ANTBP (bf16 atoms_n^T, kslot-permuted cols, [144][128] u16)
#define OFS_X     86080        // XPB: bf16 mu*X, kslot-permuted cols, [128][128] u16
#define OFS_PM    139328       // 32768 patch means
#define OFS_GOAL  172096       // 45056 goal (f32)
#define OFS_CF    4411456      // cfgb: per block 64 lanes x 16 u32 (packed bf16 B-frags)
#define OFS_PRED  8605760      // predh: bf16 j-major [144][32768] u16
#define OFS_ATB   OFS_S0
#define OFS_ANTB  OFS_S1

// k-slot permutation (X / ANTBP / state B-frags):
//   ks = 32s + 8Q + j  <->  real n = 32s + 16(j>>2) + 4Q + (j&3)
// Wave w owns slots {2w, 2w+1} (atoms 64w..64w+63). Its MFMA C/D accumulator
// (atom = 64w + 16m + 4Q + r) packs DIRECTLY into its own B-frag slots:
//   slot 2w+sp, word jj = cvt_pk(state[(sp<<1)|(jj>>1)][2(jj&1)], [..+1]).
// CRITICAL (rule #20): B-frag registers are NAMED (own0/own1/oth0/oth1), never
// runtime-indexed — a bfr[2*w+..] array goes to scratch (round-2 regression).
// CRITICAL (round-3 lesson): X A-frags must be PINNED via opaque asm, else the
// compiler sinks the loop-invariant XPB loads into the FISTA loop (VGPR=80,
// ~1.1 GB of L2 re-reads, 47 us). launch_bounds(128,2) gives the 256-reg budget.

typedef __attribute__((ext_vector_type(8))) short short8_t;
typedef __attribute__((ext_vector_type(4))) float f32x4;
typedef __attribute__((ext_vector_type(4))) uint32_t u32x4;

__device__ __forceinline__ unsigned short f2bf(float f) {      // RNE
    union { float f; uint32_t u; } x; x.f = f;
    uint32_t u = x.u;
    return (unsigned short)((u + 0x7FFFu + ((u >> 16) & 1u)) >> 16);
}
__device__ __forceinline__ unsigned short f2bh(float f) {      // round-half-up (cheap)
    union { float f; uint32_t u; } x; x.f = f;
    return (unsigned short)((x.u + 0x8000u) >> 16);
}
__device__ __forceinline__ float bf2f(unsigned short u) {
    union { float f; uint32_t i; } x; x.i = ((uint32_t)u) << 16; return x.f;
}
// pack two f32 -> packed bf16 pair (a->low, b->high), round-half-up (VALU fallback)
__device__ __forceinline__ uint32_t pack_bf(float a, float b) {
    union { float f; uint32_t u; } xa, xb; xa.f = a; xb.f = b;
    return __builtin_amdgcn_perm(xb.u + 0x8000u, xa.u + 0x8000u, 0x07060302u);
}
// single-instruction pack (RNE)
__device__ __forceinline__ uint32_t cvt_pk(float a, float b) {
    uint32_t r;
    asm("v_cvt_pk_bf16_f32 %0, %1, %2" : "=v"(r) : "v"(a), "v"(b));
    return r;
}

// ---- setup: block 0 = norm + bf16 gram + 8x power squarings + Rayleigh (1024 thr);
//      blocks 1..45 = goal copy + patch means (run hidden under block 0's chain). ----
#define PSTR 136
__global__ __launch_bounds__(1024) void k_setup(const float* atoms, const float* mu_p,
                                                float* ws, const float* y) {
    __shared__ unsigned short ABf[128 * 168];       // 43008 B
    __shared__ unsigned short Pb[2][128 * PSTR];    // 69632 B
    __shared__ float tr_arr[10];
    __shared__ float v[128];
    __shared__ float red[256];
    int t = threadIdx.x;
    if (blockIdx.x != 0) {                          // worker blocks: goal + pm
        int e = (blockIdx.x - 1) * 1024 + t;        // < 46080
        if (e < 45000) ws[OFS_GOAL + e] = y[e];
        if (e < 32768) {
            int b = e >> 12, pi = (e >> 6) & 63, pj = e & 63;
            const float* yb = y + b * 5625;
            float s = 0.f;
            for (int di = 0; di < 12; ++di) {
                const float* row = yb + (pi + di) * 75 + pj;
                #pragma unroll
                for (int dj = 0; dj < 12; ++dj) s += row[dj];
            }
            ws[OFS_PM + e] = s * (1.0f / 144.0f);
        }
        return;
    }
    int lane = t & 63, w = t >> 6;
    int col = lane & 15, quad = lane >> 4;
    if (t < 10) tr_arr[t] = (t == 0) ? 128.0f : 0.f;

    // ---- norm: 8 threads/atom, width-8 shfl reductions ----
    {
        int a = t >> 3, sub = t & 7;
        const float* ap = atoms + a * AA + sub * 18;
        float s = 0.f;
        #pragma unroll
        for (int k = 0; k < 18; ++k) s += ap[k];
        s += __shfl_xor(s, 1, 8); s += __shfl_xor(s, 2, 8); s += __shfl_xor(s, 4, 8);
        float mean = s * (1.0f / 144.0f);
        float ss = 0.f;
        #pragma unroll
        for (int k = 0; k < 18; ++k) { float d = ap[k] - mean; ss = fmaf(d, d, ss); }
        ss += __shfl_xor(ss, 1, 8); ss += __shfl_xor(ss, 2, 8); ss += __shfl_xor(ss, 4, 8);
        float rn = 1.0f / sqrtf(ss);
        #pragma unroll
        for (int k = 0; k < 18; ++k) {
            float av = (ap[k] - mean) * rn;
            ws[OFS_AF1 + a * AA + sub * 18 + k] = av;
            ABf[a * 168 + sub * 18 + k] = f2bf(av);
        }
        if (sub == 0) {
            #pragma unroll
            for (int k = AA; k < 160; ++k) ABf[a * 168 + k] = 0;
        }
    }
    __syncthreads();

    // ---- gram: wave w -> m-tile (w&7), g-half (w>>3) ----
    {
        uint32_t* D32 = (uint32_t*)Pb[0];
        float* G = ws + OFS_G;
        int mt = w & 7, gh = w >> 3;
        short8_t af[5];
        #pragma unroll
        for (int s = 0; s < 5; ++s)
            af[s] = *(const short8_t*)&ABf[(mt * 16 + col) * 168 + s * 32 + quad * 8];
        #pragma unroll
        for (int gi = 0; gi < 2; ++gi) {
            int g = gh * 2 + gi;
            short8_t b0[5], b1[5];
            #pragma unroll
            for (int s = 0; s < 5; ++s) {
                b0[s] = *(const short8_t*)&ABf[((2 * g) * 16 + col) * 168 + s * 32 + quad * 8];
                b1[s] = *(const short8_t*)&ABf[((2 * g + 1) * 16 + col) * 168 + s * 32 + quad * 8];
            }
            f32x4 a0 = (f32x4){0.f, 0.f, 0.f, 0.f};
            f32x4 a1 = (f32x4){0.f, 0.f, 0.f, 0.f};
            #pragma unroll
            for (int s = 0; s < 5; ++s) {
                a0 = __builtin_amdgcn_mfma_f32_16x16x32_bf16(af[s], b0[s], a0, 0, 0, 0);
                a1 = __builtin_amdgcn_mfma_f32_16x16x32_bf16(af[s], b1[s], a1, 0, 0, 0);
            }
            #pragma unroll
            for (int r = 0; r < 4; ++r) {
                int m = mt * 16 + quad * 4 + r;
                G[m * 128 + g * 32 + col] = a0[r];
                G[m * 128 + g * 32 + 16 + col] = a1[r];
                D32[m * 68 + g * 16 + col] = pack_bf(a0[r], a1[r]);
            }
        }
    }
    __syncthreads();

    // ---- power: 8 squarings; wave w -> m-tile (w&7), n-quarter (w>>3) ----
    int cur = 0;
    #pragma unroll 1
    for (int j = 0; j < 8; ++j) {
        float trn = tr_arr[j];
        float inv2 = 1.0f / (trn * trn);
        const unsigned short* S = Pb[cur];
        uint32_t* D32 = (uint32_t*)Pb[cur ^ 1];
        int mt = w & 7, nh = w >> 3;
        short8_t af[4];
        #pragma unroll
        for (int s = 0; s < 4; ++s)
            af[s] = *(const short8_t*)&S[(mt * 16 + col) * PSTR + s * 32 + quad * 8];
        #pragma unroll
        for (int pr = 0; pr < 2; ++pr) {
            int ntE = 4 * nh + 2 * pr, ntO = ntE + 1;
            short8_t bE[4], bO[4];
            #pragma unroll
            for (int s = 0; s < 4; ++s) {
                bE[s] = *(const short8_t*)&S[(ntE * 16 + col) * PSTR + s * 32 + quad * 8];
                bO[s] = *(const short8_t*)&S[(ntO * 16 + col) * PSTR + s * 32 + quad * 8];
            }
            f32x4 aE = (f32x4){0.f, 0.f, 0.f, 0.f};
            f32x4 aO = (f32x4){0.f, 0.f, 0.f, 0.f};
            #pragma unroll
            for (int s = 0; s < 4; ++s) {
                aE = __builtin_amdgcn_mfma_f32_16x16x32_bf16(af[s], bE[s], aE, 0, 0, 0);
                aO = __builtin_amdgcn_mfma_f32_16x16x32_bf16(af[s], bO[s], aO, 0, 0, 0);
            }
            int nE = ntE * 16 + col, nO = ntO * 16 + col;
            #pragma unroll
            for (int r = 0; r < 4; ++r) {
                float x0 = aE[r] * inv2, x1 = aO[r] * inv2;
                int row = mt * 16 + quad * 4 + r;
                D32[row * 68 + (ntE >> 1) * 16 + col] = pack_bf(x0, x1);
                if (row == nE) atomicAdd(&tr_arr[j + 1], x0);
                if (row == nO) atomicAdd(&tr_arr[j + 1], x1);
            }
        }
        __syncthreads();
        cur ^= 1;
    }

    // ---- Rayleigh on f32 G (8 threads/row) ----
    {
        int a = t >> 3, sub = t & 7;
        const unsigned short* S = Pb[cur];
        float s = 0.f;
        #pragma unroll
        for (int k = 0; k < 16; ++k) s += bf2f(S[a * PSTR + sub * 16 + k]);
        s += __shfl_xor(s, 1, 8); s += __shfl_xor(s, 2, 8); s += __shfl_xor(s, 4, 8);
        if (sub == 0) v[a] = s;
    }
    __syncthreads();
    {
        int a = t >> 3, sub = t & 7;
        const float* G = ws + OFS_G;
        float wv = 0.f;
        #pragma unroll
        for (int k = 0; k < 16; ++k)
            wv = fmaf(G[a * 128 + sub * 16 + k], v[sub * 16 + k], wv);
        wv += __shfl_xor(wv, 1, 8); wv += __shfl_xor(wv, 2, 8); wv += __shfl_xor(wv, 4, 8);
        if (sub == 0) { red[a] = v[a] * wv; red[128 + a] = v[a] * v[a]; }
    }
    __syncthreads();
    for (int off = 64; off > 0; off >>= 1) {
        if (t < off) { red[t] += red[t + off]; red[128 + t] += red[128 + t + off]; }
        __syncthreads();
    }
    if (t == 0) {
        float lam = red[0] / red[128];
        float mu = fmaxf(mu_p[0], 0.0f);
        float scX = 1.0f / (lam * mu);
        float scA = 1.0f / (sqrtf(lam) * sqrtf(mu));
        ws[OFS_SC + 16] = scX * mu;     // X' = mu*X scale (= 1/lam)
        ws[OFS_SC + 17] = scA;          // atoms_n scale (pred path)
        ws[OFS_SC + 18] = -scA * mu;    // q path: -mu*atoms_n (negated, mu-folded)
    }
}

// ---- finalize: scale-dependent tables (XPB / ATB / ANTBP), kslot permutation ----
__global__ __launch_bounds__(256) void k_finalize(float* ws) {
    int idx = blockIdx.x * 256 + threadIdx.x;       // grid 216 -> 55296
    float scX = ws[OFS_SC + 16], scA = ws[OFS_SC + 17], scQ = ws[OFS_SC + 18];
    if (idx < 16384) {
        // XPB: rows natural (atom out), cols kslot-permuted; value = mu*X
        int row = idx >> 7, ks = idx & 127;
        int s = ks >> 5, Q = (ks >> 3) & 3, j = ks & 7;
        int n = 32 * s + 16 * (j >> 2) + 4 * Q + (j & 3);
        ((unsigned short*)(ws + OFS_X))[idx] = f2bf(ws[OFS_G + row * 128 + n] * scX);
    } else if (idx < 36864) {
        // ATB [n=128][k=160] zero-pad, natural orders; value = -mu*atoms_n
        int e = idx - 16384;
        int n = e / 160, k = e - n * 160;
        float v = (k < 144) ? ws[OFS_AF1 + n * 144 + k] * scQ : 0.f;
        ((unsigned short*)(ws + OFS_ATB))[e] = f2bf(v);
    } else {
        // ANTBP [j=144][ks=128] kslot-permuted cols; value = atoms_n
        int e = idx - 36864;
        int jr = e >> 7, ks = e & 127;
        int s = ks >> 5, Q = (ks >> 3) & 3, j = ks & 7;
        int n = 32 * s + 16 * (j >> 2) + 4 * Q + (j & 3);
        ((unsigned short*)(ws + OFS_ANTB))[e] = f2bf(ws[OFS_AF1 + n * 144 + jr] * scA);
    }
}

// ---- fused FISTA megakernel: 2 waves/block, 16 patches/block.
//      Wave w owns 64 atoms (xfo/xfx = 64 VGPR, asm-pinned). Per iteration:
//      16 MFMA + in-register update + exchange of the wave's PACKED bf16 z-half
//      (2 ds_write_b128 / 2 ds_read_b128, double-buffered, ONE 2-wave barrier). ----
__global__ __launch_bounds__(128, 2) void k_fista(const unsigned short* XPB,
        const float* goal, const unsigned short* ATB, const unsigned short* ANTBP,
        const float* pm, uint32_t* cfgb, unsigned short* predh,
        int first, int write_cf) {
    __shared__ u32x4 Zx[2][2][2][64];           // [buf][wave][slot'][lane], 8 KiB
    int t = threadIdx.x;
    int lane = t & 63, w = t >> 6;
    int ow = w ^ 1;
    int col = lane & 15, Q = lane >> 4;
    int so0 = 2 * w, so1 = 2 * w + 1;           // own k-slots
    int sx0 = 2 * ow, sx1 = 2 * ow + 1;         // other wave's k-slots
    int blk = blockIdx.x;                       // 2048 blocks: 16 patches each
    int b = blk >> 8, pi = (blk >> 2) & 63;
    int pcol = (blk & 3) * 16 + col;            // pj of this lane's patch
    int p = blk * 16 + col;                     // global patch id
    const float* gb = goal + b * 5625 + pi * 75;

    // ---- im2col B-frags for q (natural spatial k): both waves, identical ----
    u32x4 bq[5];
    #pragma unroll
    for (int s = 0; s < 5; ++s)
        #pragma unroll
        for (int jj = 0; jj < 4; ++jj) {
            int k0 = 32 * s + 8 * Q + 2 * jj;   // even -> dj<=10, pair in-row
            float v0 = 0.f, v1 = 0.f;
            if (k0 < 144) {
                int di = k0 / 12, dj = k0 - di * 12;
                const float* r = gb + di * 75 + pcol + dj;
                v0 = r[0]; v1 = r[1];
            }
            bq[s][jj] = cvt_pk(v0, v1);
        }

    // ---- qn = (-mu*atoms_n) @ patch for the wave's 4 m-tiles ----
    f32x4 qn4[4];
    #pragma unroll
    for (int m = 0; m < 4; ++m) {
        short8_t af[5];
        #pragma unroll
        for (int s = 0; s < 5; ++s)
            af[s] = *(const short8_t*)&ATB[((w * 4 + m) * 16 + col) * 160 + 32 * s + 8 * Q];
        f32x4 a = (f32x4){0.f, 0.f, 0.f, 0.f};
        #pragma unroll
        for (int s = 0; s < 5; ++s)
            a = __builtin_amdgcn_mfma_f32_16x16x32_bf16(af[s],
                    __builtin_bit_cast(short8_t, bq[s]), a, 0, 0, 0);
        qn4[m] = a;
    }

    // ---- X' A-frags for the wave's 64 atom rows, K split own/other (64 VGPR).
    //      PINNED via opaque asm so the compiler cannot sink the loads into
    //      the loop (round-3: it reloaded from L2 every iteration). ----
    short8_t xfo[4][2], xfx[4][2];
    #pragma unroll
    for (int m = 0; m < 4; ++m) {
        const unsigned short* Xr = &XPB[((w * 4 + m) * 16 + col) * 128 + 8 * Q];
        xfo[m][0] = *(const short8_t*)&Xr[32 * so0];
        xfo[m][1] = *(const short8_t*)&Xr[32 * so1];
        xfx[m][0] = *(const short8_t*)&Xr[32 * sx0];
        xfx[m][1] = *(const short8_t*)&Xr[32 * sx1];
    }
    #pragma unroll
    for (int m = 0; m < 4; ++m)
        asm volatile("" : "+v"(xfo[m][0]), "+v"(xfo[m][1]),
                          "+v"(xfx[m][0]), "+v"(xfx[m][1]));

    // ---- state (c, z in C/D layout for own atoms; named packed B-frag regs) ----
    f32x4 c4[4], z4[4], acc4[4];
    u32x4 own0, own1, oth0, oth1;
    if (first) {
        #pragma unroll
        for (int m = 0; m < 4; ++m) c4[m] = z4[m] = (f32x4){0.f, 0.f, 0.f, 0.f};
        own0 = own1 = oth0 = oth1 = (u32x4){0u, 0u, 0u, 0u};
    } else {
        const u32x4* cp = (const u32x4*)(cfgb + ((size_t)blk * 64 + lane) * 16);
        own0 = cp[so0]; own1 = cp[so1];
        oth0 = cp[sx0]; oth1 = cp[sx1];
        #pragma unroll
        for (int jj = 0; jj < 4; ++jj) {        // unpack own slots -> f32 state
            int m = jj >> 1, r = 2 * (jj & 1);
            uint32_t p0 = own0[jj], p1 = own1[jj];
            c4[m][r]         = __builtin_bit_cast(float, p0 << 16);
            c4[m][r + 1]     = __builtin_bit_cast(float, p0 & 0xFFFF0000u);
            c4[2 + m][r]     = __builtin_bit_cast(float, p1 << 16);
            c4[2 + m][r + 1] = __builtin_bit_cast(float, p1 & 0xFFFF0000u);
        }
        #pragma unroll
        for (int m = 0; m < 4; ++m) z4[m] = c4[m];
    }

    // acc = z@X' - q'  (C-in of first k-step = qn = -mu*q; own slots first)
    auto matmul = [&]() {
        #pragma unroll
        for (int m = 0; m < 4; ++m)
            acc4[m] = __builtin_amdgcn_mfma_f32_16x16x32_bf16(xfo[m][0],
                          __builtin_bit_cast(short8_t, own0), qn4[m], 0, 0, 0);
        #pragma unroll
        for (int m = 0; m < 4; ++m)
            acc4[m] = __builtin_amdgcn_mfma_f32_16x16x32_bf16(xfo[m][1],
                          __builtin_bit_cast(short8_t, own1), acc4[m], 0, 0, 0);
        #pragma unroll
        for (int m = 0; m < 4; ++m)
            acc4[m] = __builtin_amdgcn_mfma_f32_16x16x32_bf16(xfx[m][0],
                          __builtin_bit_cast(short8_t, oth0), acc4[m], 0, 0, 0);
        #pragma unroll
        for (int m = 0; m < 4; ++m)
            acc4[m] = __builtin_amdgcn_mfma_f32_16x16x32_bf16(xfx[m][1],
                          __builtin_bit_cast(short8_t, oth1), acc4[m], 0, 0, 0);
    };
    // own C/D -> own B-frag slots (compile-time indices only)
    auto pack = [&](f32x4 (&src)[4]) {
        #pragma unroll
        for (int jj = 0; jj < 4; ++jj) {
            int m = jj >> 1, r = 2 * (jj & 1);
            own0[jj] = cvt_pk(src[m][r], src[m][r + 1]);
            own1[jj] = cvt_pk(src[2 + m][r], src[2 + m][r + 1]);
        }
    };
    auto exchange = [&](int buf) {              // write own half, sync, read other half
        Zx[buf][w][0][lane] = own0;
        Zx[buf][w][1][lane] = own1;
        __syncthreads();
        oth0 = Zx[buf][ow][0][lane];
        oth1 = Zx[buf][ow][1][lane];
    };

    float tm = 1.0f;
    #pragma unroll 2
    for (int it = 0; it < 14; ++it) {           // FISTA iters 1..14 (update z)
        matmul();
        float tn = 0.5f * (1.0f + sqrtf(1.0f + 4.0f * tm * tm));
        float fm = (tm - 1.0f) / tn;
        tm = tn;
        f32x4 fm4 = (f32x4){fm, fm, fm, fm};
        #pragma unroll
        for (int m = 0; m < 4; ++m) {
            f32x4 u = z4[m] - acc4[m];          // z - mu*(z@X - q)
            f32x4 cl;
            #pragma unroll
            for (int e = 0; e < 4; ++e) cl[e] = __builtin_amdgcn_fmed3f(u[e], -LAM, LAM);
            f32x4 cn = u - cl;
            z4[m] = cn + fm4 * (cn - c4[m]);
            c4[m] = cn;
        }
        pack(z4);
        exchange(it & 1);
    }
    {   // FISTA iter 15: c15 only (z15 never consumed)
        matmul();
        #pragma unroll
        for (int m = 0; m < 4; ++m) {
            f32x4 u = z4[m] - acc4[m];
            f32x4 cl;
            #pragma unroll
            for (int e = 0; e < 4; ++e) cl[e] = __builtin_amdgcn_fmed3f(u[e], -LAM, LAM);
            c4[m] = u - cl;
        }
        pack(c4);
        exchange(0);
    }
    {   // final differentiable step: cf = prox(c15 - mu*(c15@X - q))
        matmul();
        #pragma unroll
        for (int m = 0; m < 4; ++m) {
            f32x4 u = c4[m] - acc4[m];
            f32x4 cl;
            #pragma unroll
            for (int e = 0; e < 4; ++e) cl[e] = __builtin_amdgcn_fmed3f(u[e], -LAM, LAM);
            c4[m] = u - cl;
        }
        pack(c4);
        exchange(1);
    }
    if (write_cf) {                             // persist full cf (own slots per wave)
        u32x4* cp = (u32x4*)(cfgb + ((size_t)blk * 64 + lane) * 16);
        cp[so0] = own0;
        cp[so1] = own1;
    }

    // ---- pred (j-major, split across waves): predh[j][p] = bf16(cf@atoms_n + pm) ----
    {
        float pmv = pm[p];
        f32x4 pm4 = (f32x4){pmv, pmv, pmv, pmv};
        int jm0 = w ? 5 : 0, jmN = w ? 4 : 5;
        #pragma unroll
        for (int ji = 0; ji < 5; ++ji) {
            if (ji < jmN) {
                int jm = jm0 + ji;
                const unsigned short* Ar = &ANTBP[(jm * 16 + col) * 128 + 8 * Q];
                short8_t ao0 = *(const short8_t*)&Ar[32 * so0];
                short8_t ao1 = *(const short8_t*)&Ar[32 * so1];
                short8_t ax0 = *(const short8_t*)&Ar[32 * sx0];
                short8_t ax1 = *(const short8_t*)&Ar[32 * sx1];
                f32x4 a = pm4;
                a = __builtin_amdgcn_mfma_f32_16x16x32_bf16(ao0,
                        __builtin_bit_cast(short8_t, own0), a, 0, 0, 0);
                a = __builtin_amdgcn_mfma_f32_16x16x32_bf16(ao1,
                        __builtin_bit_cast(short8_t, own1), a, 0, 0, 0);
                a = __builtin_amdgcn_mfma_f32_16x16x32_bf16(ax0,
                        __builtin_bit_cast(short8_t, oth0), a, 0, 0, 0);
                a = __builtin_amdgcn_mfma_f32_16x16x32_bf16(ax1,
                        __builtin_bit_cast(short8_t, oth1), a, 0, 0, 0);
                #pragma unroll
                for (int r = 0; r < 4; ++r)
                    predh[(jm * 16 + 4 * Q + r) * 32768 + p] = f2bh(a[r]);
            }
        }
    }
}

// ---- fold via LDS staging: block = (output row i, batch b); j-major bf16 pred. ----
__global__ __launch_bounds__(256) void k_fold(const float* y, const float* beta_p,
                                              const unsigned short* predh, float* goal,
                                              float* out, int write_out) {
    __shared__ float P[12 * 832];              // 39,936 B
    int i = blockIdx.x, b = blockIdx.y;
    int t = threadIdx.x;
    for (int di = 0; di < 12; ++di) {
        int pi = i - di;
        if ((unsigned)pi >= 64u) continue;     // uniform per block
        int base = (b << 12) + (pi << 6);
        #pragma unroll
        for (int it = 0; it < 3; ++it) {
            int e = t + it * 256;              // < 768 = 12 dj * 64 pj
            int dj = e >> 6, pj = e & 63;      // consecutive t -> consecutive pj
            P[di * 832 + pj * 13 + dj] = bf2f(predh[(di * 12 + dj) * 32768 + base + pj]);
        }
    }
    __syncthreads();
    if (t >= 75) return;
    int j = t;
    float S = 0.f;
    for (int di = 0; di < 12; ++di) {
        if ((unsigned)(i - di) >= 64u) continue;
        const float* Pd = &P[di * 832];
        #pragma unroll
        for (int dj = 0; dj < 12; ++dj) {
            int pj = j - dj;
            if ((unsigned)pj >= 64u) continue;
            S += Pd[pj * 13 + dj];
        }
    }
    int ci = min(i, 11) - max(i - 63, 0) + 1;
    int cj = min(j, 11) - max(j - 63, 0) + 1;
    float beta = fmaxf(beta_p[0], 0.0f);
    int idx = i * 75 + j;
    float yv = y[b * 5625 + idx];
    float g = (yv + beta * S) / (1.0f + beta * (float)(ci * cj));
    if (write_out) out[b * 5625 + idx] = g;
    else           goal[b * 5625 + idx] = g;
}

extern "C" void kernel_launch(void* const* d_in, const int* in_sizes, int n_in,
                              void* d_out, int out_size, void* d_ws, size_t ws_size,
                              hipStream_t stream) {
    const float* y     = (const float*)d_in[0];
    const float* atoms = (const float*)d_in[1];
    const float* beta  = (const float*)d_in[2];
    const float* mu    = (const float*)d_in[3];
    float* out = (float*)d_out;
    float* ws = (float*)d_ws;

    k_setup<<<46, 1024, 0, stream>>>(atoms, mu, ws, y);   // block0 chain + workers goal/pm
    k_finalize<<<216, 256, 0, stream>>>(ws);              // XPB + ATB + ANTBP

    for (int u = 0; u < 2; ++u) {
        k_fista<<<2048, 128, 0, stream>>>((const unsigned short*)(ws + OFS_X),
                                          ws + OFS_GOAL,
                                          (const unsigned short*)(ws + OFS_ATB),
                                          (const unsigned short*)(ws + OFS_ANTB),
                                          ws + OFS_PM, (uint32_t*)(ws + OFS_CF),
                                          (unsigned short*)(ws + OFS_PRED),
                                          u == 0 ? 1 : 0, u == 0 ? 1 : 0);
        k_fold<<<dim3(75, 8), 256, 0, stream>>>(y, beta,
                                                (const unsigned short*)(ws + OFS_PRED),
                                                ws + OFS_GOAL, out, u == 1 ? 1 : 0);
    }
}

// Round 5
// 187.302 us; speedup vs baseline: 1.0812x; 1.0812x over previous
//
#include <hip/hip_runtime.h>
#include <stdint.h>

// Problem constants
#define AA 144          // ATOM*ATOM
#define LAM 0.1f

// ---- workspace layout (float offsets) ----
#define OFS_SC    0            // 64 scalars: [16]=scX*mu, [17]=scA, [18]=-scA*mu
#define OFS_AF1   64           // 128*144 row-normalized zero-mean atoms
#define OFS_G     36928        // 128*128 gram (f32)
#define OFS_S0    53312        // ATB (bf16 -mu*atoms_n, [128][160] u16, natural order)
#define OFS_S1    69696        // ANTBP (bf16 atoms_n^T, kslot-permuted cols, [144][128] u16)
#define OFS_X     86080        // XPB: bf16 mu*X, kslot-permuted cols, [128][128] u16
#define OFS_PM    139328       // 32768 patch means
#define OFS_GOAL  172096       // 45056 goal (f32)
#define OFS_CF    4411456      // cfgb: per 16-patch tile 64 lanes x 16 u32 (bf16 B-frags)
#define OFS_PRED  8605760      // predh: bf16 j-major [144][32768] u16
#define OFS_ATB   OFS_S0
#define OFS_ANTB  OFS_S1

// k-slot permutation (X / ANTBP / state B-frags):
//   ks = 32s + 8Q + j  <->  real n = 32s + 16(j>>2) + 4Q + (j&3)
// Wave w owns slots {2w, 2w+1} (atoms 64w..64w+63). Its MFMA C/D accumulator
// (atom = 64w + 16m + 4Q + r) packs DIRECTLY into its own B-frag slots:
//   slot 2w+sp, word jj = cvt_pk(state[(sp<<1)|(jj>>1)][2(jj&1)], [..+1]).
// Round-2 lesson (rule #20): B-frag regs NAMED, never runtime-indexed.
// Round-4 lesson: X frags already register-resident (AGPR); the 47us plateau
// was chain-latency exposure. Fix: DUAL independent tiles per wave (A,B share
// the X frags) so MFMA latency / LDS round-trip / barrier hide under the
// other tile's independent work.

typedef __attribute__((ext_vector_type(8))) short short8_t;
typedef __attribute__((ext_vector_type(4))) float f32x4;
typedef __attribute__((ext_vector_type(4))) uint32_t u32x4;

__device__ __forceinline__ unsigned short f2bf(float f) {      // RNE
    union { float f; uint32_t u; } x; x.f = f;
    uint32_t u = x.u;
    return (unsigned short)((u + 0x7FFFu + ((u >> 16) & 1u)) >> 16);
}
__device__ __forceinline__ unsigned short f2bh(float f) {      // round-half-up (cheap)
    union { float f; uint32_t u; } x; x.f = f;
    return (unsigned short)((x.u + 0x8000u) >> 16);
}
__device__ __forceinline__ float bf2f(unsigned short u) {
    union { float f; uint32_t i; } x; x.i = ((uint32_t)u) << 16; return x.f;
}
// pack two f32 -> packed bf16 pair (a->low, b->high), round-half-up (VALU fallback)
__device__ __forceinline__ uint32_t pack_bf(float a, float b) {
    union { float f; uint32_t u; } xa, xb; xa.f = a; xb.f = b;
    return __builtin_amdgcn_perm(xb.u + 0x8000u, xa.u + 0x8000u, 0x07060302u);
}
// single-instruction pack (RNE)
__device__ __forceinline__ uint32_t cvt_pk(float a, float b) {
    uint32_t r;
    asm("v_cvt_pk_bf16_f32 %0, %1, %2" : "=v"(r) : "v"(a), "v"(b));
    return r;
}

// ---- setup: block 0 = norm + bf16 gram + 8x power squarings + Rayleigh (1024 thr);
//      blocks 1..45 = goal copy + patch means (run hidden under block 0's chain). ----
#define PSTR 136
__global__ __launch_bounds__(1024) void k_setup(const float* atoms, const float* mu_p,
                                                float* ws, const float* y) {
    __shared__ unsigned short ABf[128 * 168];       // 43008 B
    __shared__ unsigned short Pb[2][128 * PSTR];    // 69632 B
    __shared__ float tr_arr[10];
    __shared__ float v[128];
    __shared__ float red[256];
    int t = threadIdx.x;
    if (blockIdx.x != 0) {                          // worker blocks: goal + pm
        int e = (blockIdx.x - 1) * 1024 + t;        // < 46080
        if (e < 45000) ws[OFS_GOAL + e] = y[e];
        if (e < 32768) {
            int b = e >> 12, pi = (e >> 6) & 63, pj = e & 63;
            const float* yb = y + b * 5625;
            float s = 0.f;
            for (int di = 0; di < 12; ++di) {
                const float* row = yb + (pi + di) * 75 + pj;
                #pragma unroll
                for (int dj = 0; dj < 12; ++dj) s += row[dj];
            }
            ws[OFS_PM + e] = s * (1.0f / 144.0f);
        }
        return;
    }
    int lane = t & 63, w = t >> 6;
    int col = lane & 15, quad = lane >> 4;
    if (t < 10) tr_arr[t] = (t == 0) ? 128.0f : 0.f;

    // ---- norm: 8 threads/atom, width-8 shfl reductions ----
    {
        int a = t >> 3, sub = t & 7;
        const float* ap = atoms + a * AA + sub * 18;
        float s = 0.f;
        #pragma unroll
        for (int k = 0; k < 18; ++k) s += ap[k];
        s += __shfl_xor(s, 1, 8); s += __shfl_xor(s, 2, 8); s += __shfl_xor(s, 4, 8);
        float mean = s * (1.0f / 144.0f);
        float ss = 0.f;
        #pragma unroll
        for (int k = 0; k < 18; ++k) { float d = ap[k] - mean; ss = fmaf(d, d, ss); }
        ss += __shfl_xor(ss, 1, 8); ss += __shfl_xor(ss, 2, 8); ss += __shfl_xor(ss, 4, 8);
        float rn = 1.0f / sqrtf(ss);
        #pragma unroll
        for (int k = 0; k < 18; ++k) {
            float av = (ap[k] - mean) * rn;
            ws[OFS_AF1 + a * AA + sub * 18 + k] = av;
            ABf[a * 168 + sub * 18 + k] = f2bf(av);
        }
        if (sub == 0) {
            #pragma unroll
            for (int k = AA; k < 160; ++k) ABf[a * 168 + k] = 0;
        }
    }
    __syncthreads();

    // ---- gram: wave w -> m-tile (w&7), g-half (w>>3) ----
    {
        uint32_t* D32 = (uint32_t*)Pb[0];
        float* G = ws + OFS_G;
        int mt = w & 7, gh = w >> 3;
        short8_t af[5];
        #pragma unroll
        for (int s = 0; s < 5; ++s)
            af[s] = *(const short8_t*)&ABf[(mt * 16 + col) * 168 + s * 32 + quad * 8];
        #pragma unroll
        for (int gi = 0; gi < 2; ++gi) {
            int g = gh * 2 + gi;
            short8_t b0[5], b1[5];
            #pragma unroll
            for (int s = 0; s < 5; ++s) {
                b0[s] = *(const short8_t*)&ABf[((2 * g) * 16 + col) * 168 + s * 32 + quad * 8];
                b1[s] = *(const short8_t*)&ABf[((2 * g + 1) * 16 + col) * 168 + s * 32 + quad * 8];
            }
            f32x4 a0 = (f32x4){0.f, 0.f, 0.f, 0.f};
            f32x4 a1 = (f32x4){0.f, 0.f, 0.f, 0.f};
            #pragma unroll
            for (int s = 0; s < 5; ++s) {
                a0 = __builtin_amdgcn_mfma_f32_16x16x32_bf16(af[s], b0[s], a0, 0, 0, 0);
                a1 = __builtin_amdgcn_mfma_f32_16x16x32_bf16(af[s], b1[s], a1, 0, 0, 0);
            }
            #pragma unroll
            for (int r = 0; r < 4; ++r) {
                int m = mt * 16 + quad * 4 + r;
                G[m * 128 + g * 32 + col] = a0[r];
                G[m * 128 + g * 32 + 16 + col] = a1[r];
                D32[m * 68 + g * 16 + col] = pack_bf(a0[r], a1[r]);
            }
        }
    }
    __syncthreads();

    // ---- power: 8 squarings; wave w -> m-tile (w&7), n-quarter (w>>3) ----
    int cur = 0;
    #pragma unroll 1
    for (int j = 0; j < 8; ++j) {
        float trn = tr_arr[j];
        float inv2 = 1.0f / (trn * trn);
        const unsigned short* S = Pb[cur];
        uint32_t* D32 = (uint32_t*)Pb[cur ^ 1];
        int mt = w & 7, nh = w >> 3;
        short8_t af[4];
        #pragma unroll
        for (int s = 0; s < 4; ++s)
            af[s] = *(const short8_t*)&S[(mt * 16 + col) * PSTR + s * 32 + quad * 8];
        #pragma unroll
        for (int pr = 0; pr < 2; ++pr) {
            int ntE = 4 * nh + 2 * pr, ntO = ntE + 1;
            short8_t bE[4], bO[4];
            #pragma unroll
            for (int s = 0; s < 4; ++s) {
                bE[s] = *(const short8_t*)&S[(ntE * 16 + col) * PSTR + s * 32 + quad * 8];
                bO[s] = *(const short8_t*)&S[(ntO * 16 + col) * PSTR + s * 32 + quad * 8];
            }
            f32x4 aE = (f32x4){0.f, 0.f, 0.f, 0.f};
            f32x4 aO = (f32x4){0.f, 0.f, 0.f, 0.f};
            #pragma unroll
            for (int s = 0; s < 4; ++s) {
                aE = __builtin_amdgcn_mfma_f32_16x16x32_bf16(af[s], bE[s], aE, 0, 0, 0);
                aO = __builtin_amdgcn_mfma_f32_16x16x32_bf16(af[s], bO[s], aO, 0, 0, 0);
            }
            int nE = ntE * 16 + col, nO = ntO * 16 + col;
            #pragma unroll
            for (int r = 0; r < 4; ++r) {
                float x0 = aE[r] * inv2, x1 = aO[r] * inv2;
                int row = mt * 16 + quad * 4 + r;
                D32[row * 68 + (ntE >> 1) * 16 + col] = pack_bf(x0, x1);
                if (row == nE) atomicAdd(&tr_arr[j + 1], x0);
                if (row == nO) atomicAdd(&tr_arr[j + 1], x1);
            }
        }
        __syncthreads();
        cur ^= 1;
    }

    // ---- Rayleigh on f32 G (8 threads/row) ----
    {
        int a = t >> 3, sub = t & 7;
        const unsigned short* S = Pb[cur];
        float s = 0.f;
        #pragma unroll
        for (int k = 0; k < 16; ++k) s += bf2f(S[a * PSTR + sub * 16 + k]);
        s += __shfl_xor(s, 1, 8); s += __shfl_xor(s, 2, 8); s += __shfl_xor(s, 4, 8);
        if (sub == 0) v[a] = s;
    }
    __syncthreads();
    {
        int a = t >> 3, sub = t & 7;
        const float* G = ws + OFS_G;
        float wv = 0.f;
        #pragma unroll
        for (int k = 0; k < 16; ++k)
            wv = fmaf(G[a * 128 + sub * 16 + k], v[sub * 16 + k], wv);
        wv += __shfl_xor(wv, 1, 8); wv += __shfl_xor(wv, 2, 8); wv += __shfl_xor(wv, 4, 8);
        if (sub == 0) { red[a] = v[a] * wv; red[128 + a] = v[a] * v[a]; }
    }
    __syncthreads();
    for (int off = 64; off > 0; off >>= 1) {
        if (t < off) { red[t] += red[t + off]; red[128 + t] += red[128 + t + off]; }
        __syncthreads();
    }
    if (t == 0) {
        float lam = red[0] / red[128];
        float mu = fmaxf(mu_p[0], 0.0f);
        float scX = 1.0f / (lam * mu);
        float scA = 1.0f / (sqrtf(lam) * sqrtf(mu));
        ws[OFS_SC + 16] = scX * mu;     // X' = mu*X scale (= 1/lam)
        ws[OFS_SC + 17] = scA;          // atoms_n scale (pred path)
        ws[OFS_SC + 18] = -scA * mu;    // q path: -mu*atoms_n (negated, mu-folded)
    }
}

// ---- finalize: scale-dependent tables (XPB / ATB / ANTBP), kslot permutation ----
__global__ __launch_bounds__(256) void k_finalize(float* ws) {
    int idx = blockIdx.x * 256 + threadIdx.x;       // grid 216 -> 55296
    float scX = ws[OFS_SC + 16], scA = ws[OFS_SC + 17], scQ = ws[OFS_SC + 18];
    if (idx < 16384) {
        // XPB: rows natural (atom out), cols kslot-permuted; value = mu*X
        int row = idx >> 7, ks = idx & 127;
        int s = ks >> 5, Q = (ks >> 3) & 3, j = ks & 7;
        int n = 32 * s + 16 * (j >> 2) + 4 * Q + (j & 3);
        ((unsigned short*)(ws + OFS_X))[idx] = f2bf(ws[OFS_G + row * 128 + n] * scX);
    } else if (idx < 36864) {
        // ATB [n=128][k=160] zero-pad, natural orders; value = -mu*atoms_n
        int e = idx - 16384;
        int n = e / 160, k = e - n * 160;
        float v = (k < 144) ? ws[OFS_AF1 + n * 144 + k] * scQ : 0.f;
        ((unsigned short*)(ws + OFS_ATB))[e] = f2bf(v);
    } else {
        // ANTBP [j=144][ks=128] kslot-permuted cols; value = atoms_n
        int e = idx - 36864;
        int jr = e >> 7, ks = e & 127;
        int s = ks >> 5, Q = (ks >> 3) & 3, j = ks & 7;
        int n = 32 * s + 16 * (j >> 2) + 4 * Q + (j & 3);
        ((unsigned short*)(ws + OFS_ANTB))[e] = f2bf(ws[OFS_AF1 + n * 144 + jr] * scA);
    }
}

// ---- fused FISTA megakernel: 2 waves/block, TWO independent 16-patch tiles
//      (A,B) per wave sharing the X frags. Per iteration: 32 MFMA (A then B,
//      separate accs so B's issue hides A's latency), two in-register updates,
//      ONE barrier covering both tiles' packed-bf16 half exchanges. ----
__global__ __launch_bounds__(128, 2) void k_fista(const unsigned short* XPB,
        const float* goal, const unsigned short* ATB, const unsigned short* ANTBP,
        const float* pm, uint32_t* cfgb, unsigned short* predh,
        int first, int write_cf) {
    __shared__ u32x4 Zx[2][2][2][2][64];        // [buf][tile][wave][slot'][lane] 16KiB
    int t = threadIdx.x;
    int lane = t & 63, w = t >> 6;
    int ow = w ^ 1;
    int col = lane & 15, Q = lane >> 4;
    int so0 = 2 * w, so1 = 2 * w + 1;           // own k-slots
    int sx0 = 2 * ow, sx1 = 2 * ow + 1;         // other wave's k-slots
    int blk = blockIdx.x;                       // 1024 blocks: 32 patches each
    int b = blk >> 7, pi = (blk >> 1) & 63;
    int pcA = (blk & 1) * 32 + col;             // tile A pj ; tile B = +16
    int pA = blk * 32 + col, pB = pA + 16;      // global patch ids
    const float* gb = goal + b * 5625 + pi * 75;

    // ---- im2col B-frags for q, both tiles (max col = 48+15+11 = 74 < 75) ----
    u32x4 bqA[5], bqB[5];
    #pragma unroll
    for (int s = 0; s < 5; ++s)
        #pragma unroll
        for (int jj = 0; jj < 4; ++jj) {
            int k0 = 32 * s + 8 * Q + 2 * jj;   // even -> dj<=10, pair in-row
            float a0 = 0.f, a1 = 0.f, b0 = 0.f, b1 = 0.f;
            if (k0 < 144) {
                int di = k0 / 12, dj = k0 - di * 12;
                const float* r = gb + di * 75 + pcA + dj;
                a0 = r[0]; a1 = r[1];
                b0 = r[16]; b1 = r[17];
            }
            bqA[s][jj] = cvt_pk(a0, a1);
            bqB[s][jj] = cvt_pk(b0, b1);
        }

    // ---- qn = (-mu*atoms_n) @ patch, ATB frags shared across tiles ----
    f32x4 qnA[4], qnB[4];
    #pragma unroll
    for (int m = 0; m < 4; ++m) {
        f32x4 aA = (f32x4){0.f, 0.f, 0.f, 0.f};
        f32x4 aB = (f32x4){0.f, 0.f, 0.f, 0.f};
        #pragma unroll
        for (int s = 0; s < 5; ++s) {
            short8_t af = *(const short8_t*)&ATB[((w * 4 + m) * 16 + col) * 160 + 32 * s + 8 * Q];
            aA = __builtin_amdgcn_mfma_f32_16x16x32_bf16(af,
                     __builtin_bit_cast(short8_t, bqA[s]), aA, 0, 0, 0);
            aB = __builtin_amdgcn_mfma_f32_16x16x32_bf16(af,
                     __builtin_bit_cast(short8_t, bqB[s]), aB, 0, 0, 0);
        }
        qnA[m] = aA;
        qnB[m] = aB;
    }

    // ---- X' A-frags for the wave's 64 atom rows, K split own/other ----
    short8_t xfo[4][2], xfx[4][2];
    #pragma unroll
    for (int m = 0; m < 4; ++m) {
        const unsigned short* Xr = &XPB[((w * 4 + m) * 16 + col) * 128 + 8 * Q];
        xfo[m][0] = *(const short8_t*)&Xr[32 * so0];
        xfo[m][1] = *(const short8_t*)&Xr[32 * so1];
        xfx[m][0] = *(const short8_t*)&Xr[32 * sx0];
        xfx[m][1] = *(const short8_t*)&Xr[32 * sx1];
    }

    // ---- state (c, z in C/D layout for own atoms; named packed B-frag regs) ----
    f32x4 cA[4], zA[4], accA[4], cB[4], zB[4], accB[4];
    u32x4 ownA0, ownA1, othA0, othA1, ownB0, ownB1, othB0, othB1;
    if (first) {
        #pragma unroll
        for (int m = 0; m < 4; ++m) {
            cA[m] = zA[m] = (f32x4){0.f, 0.f, 0.f, 0.f};
            cB[m] = zB[m] = (f32x4){0.f, 0.f, 0.f, 0.f};
        }
        ownA0 = ownA1 = othA0 = othA1 = (u32x4){0u, 0u, 0u, 0u};
        ownB0 = ownB1 = othB0 = othB1 = (u32x4){0u, 0u, 0u, 0u};
    } else {
        const u32x4* cpA = (const u32x4*)(cfgb + ((size_t)(2 * blk) * 64 + lane) * 16);
        const u32x4* cpB = (const u32x4*)(cfgb + ((size_t)(2 * blk + 1) * 64 + lane) * 16);
        ownA0 = cpA[so0]; ownA1 = cpA[so1]; othA0 = cpA[sx0]; othA1 = cpA[sx1];
        ownB0 = cpB[so0]; ownB1 = cpB[so1]; othB0 = cpB[sx0]; othB1 = cpB[sx1];
        #pragma unroll
        for (int jj = 0; jj < 4; ++jj) {        // unpack own slots -> f32 state
            int m = jj >> 1, r = 2 * (jj & 1);
            uint32_t a0 = ownA0[jj], a1 = ownA1[jj];
            cA[m][r]         = __builtin_bit_cast(float, a0 << 16);
            cA[m][r + 1]     = __builtin_bit_cast(float, a0 & 0xFFFF0000u);
            cA[2 + m][r]     = __builtin_bit_cast(float, a1 << 16);
            cA[2 + m][r + 1] = __builtin_bit_cast(float, a1 & 0xFFFF0000u);
            uint32_t b0 = ownB0[jj], b1 = ownB1[jj];
            cB[m][r]         = __builtin_bit_cast(float, b0 << 16);
            cB[m][r + 1]     = __builtin_bit_cast(float, b0 & 0xFFFF0000u);
            cB[2 + m][r]     = __builtin_bit_cast(float, b1 << 16);
            cB[2 + m][r + 1] = __builtin_bit_cast(float, b1 & 0xFFFF0000u);
        }
        #pragma unroll
        for (int m = 0; m < 4; ++m) { zA[m] = cA[m]; zB[m] = cB[m]; }
    }

    // acc = z@X' - q'  (C-in of first k-step = qn = -mu*q; own slots first)
    auto matmul = [&](u32x4& o0, u32x4& o1, u32x4& x0, u32x4& x1,
                      f32x4 (&qn)[4], f32x4 (&acc)[4]) {
        #pragma unroll
        for (int m = 0; m < 4; ++m)
            acc[m] = __builtin_amdgcn_mfma_f32_16x16x32_bf16(xfo[m][0],
                         __builtin_bit_cast(short8_t, o0), qn[m], 0, 0, 0);
        #pragma unroll
        for (int m = 0; m < 4; ++m)
            acc[m] = __builtin_amdgcn_mfma_f32_16x16x32_bf16(xfo[m][1],
                         __builtin_bit_cast(short8_t, o1), acc[m], 0, 0, 0);
        #pragma unroll
        for (int m = 0; m < 4; ++m)
            acc[m] = __builtin_amdgcn_mfma_f32_16x16x32_bf16(xfx[m][0],
                         __builtin_bit_cast(short8_t, x0), acc[m], 0, 0, 0);
        #pragma unroll
        for (int m = 0; m < 4; ++m)
            acc[m] = __builtin_amdgcn_mfma_f32_16x16x32_bf16(xfx[m][1],
                         __builtin_bit_cast(short8_t, x1), acc[m], 0, 0, 0);
    };
    // FISTA z-update + pack(z) into own slots (compile-time indices only)
    auto do_iter = [&](f32x4 (&c4)[4], f32x4 (&z4)[4], f32x4 (&acc4)[4],
                       u32x4& o0, u32x4& o1, float fm) {
        f32x4 fm4 = (f32x4){fm, fm, fm, fm};
        #pragma unroll
        for (int m = 0; m < 4; ++m) {
            f32x4 u = z4[m] - acc4[m];          // z - mu*(z@X - q)
            f32x4 cl;
            #pragma unroll
            for (int e = 0; e < 4; ++e) cl[e] = __builtin_amdgcn_fmed3f(u[e], -LAM, LAM);
            f32x4 cn = u - cl;
            z4[m] = cn + fm4 * (cn - c4[m]);
            c4[m] = cn;
        }
        #pragma unroll
        for (int jj = 0; jj < 4; ++jj) {
            int m = jj >> 1, r = 2 * (jj & 1);
            o0[jj] = cvt_pk(z4[m][r], z4[m][r + 1]);
            o1[jj] = cvt_pk(z4[2 + m][r], z4[2 + m][r + 1]);
        }
    };
    // prox step into c + pack(c); base = z (iter 15) or c (final step)
    auto do_prox = [&](f32x4 (&base)[4], f32x4 (&c4)[4], f32x4 (&acc4)[4],
                       u32x4& o0, u32x4& o1) {
        #pragma unroll
        for (int m = 0; m < 4; ++m) {
            f32x4 u = base[m] - acc4[m];
            f32x4 cl;
            #pragma unroll
            for (int e = 0; e < 4; ++e) cl[e] = __builtin_amdgcn_fmed3f(u[e], -LAM, LAM);
            c4[m] = u - cl;
        }
        #pragma unroll
        for (int jj = 0; jj < 4; ++jj) {
            int m = jj >> 1, r = 2 * (jj & 1);
            o0[jj] = cvt_pk(c4[m][r], c4[m][r + 1]);
            o1[jj] = cvt_pk(c4[2 + m][r], c4[2 + m][r + 1]);
        }
    };
    auto exchange = [&](int buf) {              // write own halves, sync, read others
        Zx[buf][0][w][0][lane] = ownA0;
        Zx[buf][0][w][1][lane] = ownA1;
        Zx[buf][1][w][0][lane] = ownB0;
        Zx[buf][1][w][1][lane] = ownB1;
        __syncthreads();
        othA0 = Zx[buf][0][ow][0][lane];
        othA1 = Zx[buf][0][ow][1][lane];
        othB0 = Zx[buf][1][ow][0][lane];
        othB1 = Zx[buf][1][ow][1][lane];
    };

    float tm = 1.0f;
    #pragma unroll 1
    for (int it = 0; it < 14; ++it) {           // FISTA iters 1..14 (update z)
        matmul(ownA0, ownA1, othA0, othA1, qnA, accA);
        matmul(ownB0, ownB1, othB0, othB1, qnB, accB);
        float tn = 0.5f * (1.0f + sqrtf(1.0f + 4.0f * tm * tm));
        float fm = (tm - 1.0f) / tn;
        tm = tn;
        do_iter(cA, zA, accA, ownA0, ownA1, fm);
        do_iter(cB, zB, accB, ownB0, ownB1, fm);
        exchange(it & 1);
    }
    {   // FISTA iter 15: c15 only (z15 never consumed)
        matmul(ownA0, ownA1, othA0, othA1, qnA, accA);
        matmul(ownB0, ownB1, othB0, othB1, qnB, accB);
        do_prox(zA, cA, accA, ownA0, ownA1);
        do_prox(zB, cB, accB, ownB0, ownB1);
        exchange(0);
    }
    {   // final differentiable step: cf = prox(c15 - mu*(c15@X - q))
        matmul(ownA0, ownA1, othA0, othA1, qnA, accA);
        matmul(ownB0, ownB1, othB0, othB1, qnB, accB);
        do_prox(cA, cA, accA, ownA0, ownA1);
        do_prox(cB, cB, accB, ownB0, ownB1);
        exchange(1);
    }
    if (write_cf) {                             // persist full cf (own slots per wave)
        u32x4* cpA = (u32x4*)(cfgb + ((size_t)(2 * blk) * 64 + lane) * 16);
        u32x4* cpB = (u32x4*)(cfgb + ((size_t)(2 * blk + 1) * 64 + lane) * 16);
        cpA[so0] = ownA0; cpA[so1] = ownA1;
        cpB[so0] = ownB0; cpB[so1] = ownB1;
    }

    // ---- pred (j-major, jm split across waves, ANTBP frags shared by tiles) ----
    {
        float pmA = pm[pA], pmB = pm[pB];
        f32x4 pmA4 = (f32x4){pmA, pmA, pmA, pmA};
        f32x4 pmB4 = (f32x4){pmB, pmB, pmB, pmB};
        int jm0 = w ? 5 : 0, jmN = w ? 4 : 5;
        #pragma unroll
        for (int ji = 0; ji < 5; ++ji) {
            if (ji < jmN) {
                int jm = jm0 + ji;
                const unsigned short* Ar = &ANTBP[(jm * 16 + col) * 128 + 8 * Q];
                short8_t ao0 = *(const short8_t*)&Ar[32 * so0];
                short8_t ao1 = *(const short8_t*)&Ar[32 * so1];
                short8_t ax0 = *(const short8_t*)&Ar[32 * sx0];
                short8_t ax1 = *(const short8_t*)&Ar[32 * sx1];
                f32x4 a = pmA4;
                a = __builtin_amdgcn_mfma_f32_16x16x32_bf16(ao0,
                        __builtin_bit_cast(short8_t, ownA0), a, 0, 0, 0);
                a = __builtin_amdgcn_mfma_f32_16x16x32_bf16(ao1,
                        __builtin_bit_cast(short8_t, ownA1), a, 0, 0, 0);
                a = __builtin_amdgcn_mfma_f32_16x16x32_bf16(ax0,
                        __builtin_bit_cast(short8_t, othA0), a, 0, 0, 0);
                a = __builtin_amdgcn_mfma_f32_16x16x32_bf16(ax1,
                        __builtin_bit_cast(short8_t, othA1), a, 0, 0, 0);
                f32x4 bb = pmB4;
                bb = __builtin_amdgcn_mfma_f32_16x16x32_bf16(ao0,
                         __builtin_bit_cast(short8_t, ownB0), bb, 0, 0, 0);
                bb = __builtin_amdgcn_mfma_f32_16x16x32_bf16(ao1,
                         __builtin_bit_cast(short8_t, ownB1), bb, 0, 0, 0);
                bb = __builtin_amdgcn_mfma_f32_16x16x32_bf16(ax0,
                         __builtin_bit_cast(short8_t, othB0), bb, 0, 0, 0);
                bb = __builtin_amdgcn_mfma_f32_16x16x32_bf16(ax1,
                         __builtin_bit_cast(short8_t, othB1), bb, 0, 0, 0);
                #pragma unroll
                for (int r = 0; r < 4; ++r) {
                    predh[(jm * 16 + 4 * Q + r) * 32768 + pA] = f2bh(a[r]);
                    predh[(jm * 16 + 4 * Q + r) * 32768 + pB] = f2bh(bb[r]);
                }
            }
        }
    }
}

// ---- fold via LDS staging: block = (output row i, batch b); j-major bf16 pred. ----
__global__ __launch_bounds__(256) void k_fold(const float* y, const float* beta_p,
                                              const unsigned short* predh, float* goal,
                                              float* out, int write_out) {
    __shared__ float P[12 * 832];              // 39,936 B
    int i = blockIdx.x, b = blockIdx.y;
    int t = threadIdx.x;
    for (int di = 0; di < 12; ++di) {
        int pi = i - di;
        if ((unsigned)pi >= 64u) continue;     // uniform per block
        int base = (b << 12) + (pi << 6);
        #pragma unroll
        for (int it = 0; it < 3; ++it) {
            int e = t + it * 256;              // < 768 = 12 dj * 64 pj
            int dj = e >> 6, pj = e & 63;      // consecutive t -> consecutive pj
            P[di * 832 + pj * 13 + dj] = bf2f(predh[(di * 12 + dj) * 32768 + base + pj]);
        }
    }
    __syncthreads();
    if (t >= 75) return;
    int j = t;
    float S = 0.f;
    for (int di = 0; di < 12; ++di) {
        if ((unsigned)(i - di) >= 64u) continue;
        const float* Pd = &P[di * 832];
        #pragma unroll
        for (int dj = 0; dj < 12; ++dj) {
            int pj = j - dj;
            if ((unsigned)pj >= 64u) continue;
            S += Pd[pj * 13 + dj];
        }
    }
    int ci = min(i, 11) - max(i - 63, 0) + 1;
    int cj = min(j, 11) - max(j - 63, 0) + 1;
    float beta = fmaxf(beta_p[0], 0.0f);
    int idx = i * 75 + j;
    float yv = y[b * 5625 + idx];
    float g = (yv + beta * S) / (1.0f + beta * (float)(ci * cj));
    if (write_out) out[b * 5625 + idx] = g;
    else           goal[b * 5625 + idx] = g;
}

extern "C" void kernel_launch(void* const* d_in, const int* in_sizes, int n_in,
                              void* d_out, int out_size, void* d_ws, size_t ws_size,
                              hipStream_t stream) {
    const float* y     = (const float*)d_in[0];
    const float* atoms = (const float*)d_in[1];
    const float* beta  = (const float*)d_in[2];
    const float* mu    = (const float*)d_in[3];
    float* out = (float*)d_out;
    float* ws = (float*)d_ws;

    k_setup<<<46, 1024, 0, stream>>>(atoms, mu, ws, y);   // block0 chain + workers goal/pm
    k_finalize<<<216, 256, 0, stream>>>(ws);              // XPB + ATB + ANTBP

    for (int u = 0; u < 2; ++u) {
        k_fista<<<1024, 128, 0, stream>>>((const unsigned short*)(ws + OFS_X),
                                          ws + OFS_GOAL,
                                          (const unsigned short*)(ws + OFS_ATB),
                                          (const unsigned short*)(ws + OFS_ANTB),
                                          ws + OFS_PM, (uint32_t*)(ws + OFS_CF),
                                          (unsigned short*)(ws + OFS_PRED),
                                          u == 0 ? 1 : 0, u == 0 ? 1 : 0);
        k_fold<<<dim3(75, 8), 256, 0, stream>>>(y, beta,
                                                (const unsigned short*)(ws + OFS_PRED),
                                                ws + OFS_GOAL, out, u == 1 ? 1 : 0);
    }
}